// Round 1
// baseline (1285.246 us; speedup 1.0000x reference)
//
#include <hip/hip_runtime.h>
#include <cstdint>
#include <cstddef>

#define NT   8192
#define DIN  1024
#define DFF  4096
#define DOUT 1024
#define NEXP 8

typedef float  f32x4v __attribute__((ext_vector_type(4)));
typedef short  s16x8  __attribute__((ext_vector_type(8)));
typedef short  s16x4  __attribute__((ext_vector_type(4)));

__device__ __forceinline__ ushort f2bf(float f) {
  union { float f; uint32_t u; } c; c.f = f;
  uint32_t u = c.u;
  return (ushort)((u + 0x7fffu + ((u >> 16) & 1u)) >> 16);  // RNE
}

// ---------------- router: logits, softmax, argmax, counts, probsums ----------
__global__ void router_kernel(const float* __restrict__ x, const float* __restrict__ sw,
                              const float* __restrict__ sb,
                              int* __restrict__ routes, int* __restrict__ posArr,
                              float* __restrict__ pmaxArr,
                              int* __restrict__ cnt, float* __restrict__ probsum) {
  const int lane = threadIdx.x & 63;
  const int t = (blockIdx.x * blockDim.x + threadIdx.x) >> 6;  // one wave per token
  if (t >= NT) return;
  const float* xr = x + (size_t)t * DIN;
  float acc[NEXP];
#pragma unroll
  for (int e = 0; e < NEXP; e++) acc[e] = 0.0f;
  for (int i = lane; i < DIN; i += 64) {
    float xv = xr[i];
    const float4 s0 = *(const float4*)(sw + (size_t)i * NEXP);
    const float4 s1 = *(const float4*)(sw + (size_t)i * NEXP + 4);
    acc[0] += xv * s0.x; acc[1] += xv * s0.y; acc[2] += xv * s0.z; acc[3] += xv * s0.w;
    acc[4] += xv * s1.x; acc[5] += xv * s1.y; acc[6] += xv * s1.z; acc[7] += xv * s1.w;
  }
#pragma unroll
  for (int e = 0; e < NEXP; e++) {
#pragma unroll
    for (int off = 32; off > 0; off >>= 1) acc[e] += __shfl_xor(acc[e], off, 64);
  }
  float lg[NEXP];
#pragma unroll
  for (int e = 0; e < NEXP; e++) lg[e] = acc[e] + sb[e];
  float m = lg[0]; int am = 0;
#pragma unroll
  for (int e = 1; e < NEXP; e++) { if (lg[e] > m) { m = lg[e]; am = e; } }
  float pe[NEXP]; float esum = 0.0f;
#pragma unroll
  for (int e = 0; e < NEXP; e++) { pe[e] = expf(lg[e] - m); esum += pe[e]; }
  const float inv = 1.0f / esum;
  if (lane == 0) {
    routes[t] = am;
    pmaxArr[t] = inv;                 // pe[am] == 1
    posArr[t] = atomicAdd(&cnt[am], 1);
#pragma unroll
    for (int e = 0; e < NEXP; e++) atomicAdd(&probsum[e], pe[e] * inv);
  }
}

// ---------------- offsets (exclusive scan of 8) + aux loss -------------------
__global__ void offsets_aux_kernel(const int* __restrict__ cnt, const float* __restrict__ probsum,
                                   int* __restrict__ offsets, float* __restrict__ auxout) {
  if (threadIdx.x == 0) {
    int o = 0; float aux = 0.0f;
    for (int e = 0; e < NEXP; e++) {
      offsets[e] = o; o += cnt[e];
      aux += (float)cnt[e] * probsum[e];
    }
    offsets[NEXP] = o;
    auxout[0] = aux * ((float)NEXP / (float)NT);
  }
}

// ---------------- gather tokens into expert-contiguous bf16 rows -------------
__global__ void gather_kernel(const float* __restrict__ x, const int* __restrict__ routes,
                              const int* __restrict__ posArr, const int* __restrict__ offsets,
                              int* __restrict__ perm, ushort* __restrict__ Xg) {
  const int lane = threadIdx.x & 63;
  const int t = (blockIdx.x * blockDim.x + threadIdx.x) >> 6;
  if (t >= NT) return;
  const int slot = offsets[routes[t]] + posArr[t];
  if (lane == 0) perm[slot] = t;
  const float* src = x + (size_t)t * DIN;
  ushort* dst = Xg + (size_t)slot * DIN;
#pragma unroll
  for (int half = 0; half < 2; half++) {
    int i = half * 512 + lane * 8;
    float4 v0 = *(const float4*)(src + i);
    float4 v1 = *(const float4*)(src + i + 4);
    s16x8 p;
    p[0] = (short)f2bf(v0.x); p[1] = (short)f2bf(v0.y);
    p[2] = (short)f2bf(v0.z); p[3] = (short)f2bf(v0.w);
    p[4] = (short)f2bf(v1.x); p[5] = (short)f2bf(v1.y);
    p[6] = (short)f2bf(v1.z); p[7] = (short)f2bf(v1.w);
    *(s16x8*)(dst + i) = p;
  }
}

// ---------------- transpose + fp32->bf16: [E][K][N] -> [E][N][K] -------------
__global__ void transpose_cvt_kernel(const float* __restrict__ src, ushort* __restrict__ dst,
                                     const int K, const int N) {
  __shared__ float tile[64][65];
  const int ntn = N >> 6;
  const int ntk = K >> 6;
  int b = blockIdx.x;
  const int tn = b % ntn; b /= ntn;
  const int tk = b % ntk; const int e = b / ntk;
  const float* s = src + ((size_t)e * K + (size_t)tk * 64) * N + (size_t)tn * 64;
  const int c4 = (threadIdx.x & 15) * 4;
  const int r0 = threadIdx.x >> 4;  // 0..15
#pragma unroll
  for (int p = 0; p < 4; p++) {
    const int row = r0 + p * 16;
    float4 v = *(const float4*)(s + (size_t)row * N + c4);
    tile[row][c4 + 0] = v.x; tile[row][c4 + 1] = v.y;
    tile[row][c4 + 2] = v.z; tile[row][c4 + 3] = v.w;
  }
  __syncthreads();
  ushort* d = dst + ((size_t)e * N + (size_t)tn * 64) * K + (size_t)tk * 64;
#pragma unroll
  for (int p = 0; p < 4; p++) {
    const int nrow = r0 + p * 16;
    s16x4 o;
    o[0] = (short)f2bf(tile[c4 + 0][nrow]);
    o[1] = (short)f2bf(tile[c4 + 1][nrow]);
    o[2] = (short)f2bf(tile[c4 + 2][nrow]);
    o[3] = (short)f2bf(tile[c4 + 3][nrow]);
    *(s16x4*)(d + (size_t)nrow * K + c4) = o;
  }
}

// ---------------- grouped GEMM, 128x128 tile, BK=32, m97-style staging -------
#define GLD16(g, l)                                                                        \
  __builtin_amdgcn_global_load_lds((const __attribute__((address_space(1))) uint32_t*)(g), \
                                   (__attribute__((address_space(3))) uint32_t*)(l), 16, 0, 0)

template <int EPI>
__global__ __launch_bounds__(256) void moe_gemm_kernel(
    const ushort* __restrict__ A,   // [slots][K] bf16, expert-contiguous rows
    const ushort* __restrict__ BT,  // [E][N][K] bf16
    const float* __restrict__ bias, // [E][N]
    const int* __restrict__ offsets,
    ushort* __restrict__ Hout,      // EPI==0: [slots][N] bf16
    float* __restrict__ Y,          // EPI==1: [NT][N] fp32 (scatter)
    const int* __restrict__ perm, const float* __restrict__ pmaxArr,
    const int K, const int N) {
  __shared__ ushort sA[128 * 32];
  __shared__ ushort sB[128 * 32];
  const int e = blockIdx.z;
  const int mlimit = offsets[e + 1];
  const int m0 = offsets[e] + blockIdx.y * 128;
  if (m0 >= mlimit) return;
  const int n0 = blockIdx.x * 128;
  const int tid = threadIdx.x;
  const int lane = tid & 63;
  const int w = tid >> 6;
  const int wr = w >> 1, wc = w & 1;

  const ushort* ga = A + (size_t)(m0 + 32 * w + (lane >> 2)) * K + (size_t)(lane & 3) * 8;
  const ushort* gb = BT + ((size_t)e * N + n0 + 32 * w + (lane >> 2)) * K + (size_t)(lane & 3) * 8;
  ushort* lA = sA + w * 1024;  // chunks 2w, 2w+1 (512 elems = 1KB each)
  ushort* lB = sB + w * 1024;
  const size_t rowstep = (size_t)16 * K;

  f32x4v acc[4][4];
#pragma unroll
  for (int i = 0; i < 4; i++)
#pragma unroll
    for (int j = 0; j < 4; j++) acc[i][j] = (f32x4v)0.0f;

  const int rsel = lane & 15;
  const int ko = (lane >> 4) * 8;

  for (int k0 = 0; k0 < K; k0 += 32) {
    GLD16(ga, lA);
    GLD16(ga + rowstep, lA + 512);
    GLD16(gb, lB);
    GLD16(gb + rowstep, lB + 512);
    ga += 32; gb += 32;
    __syncthreads();
    s16x8 af[4], bq[4];
#pragma unroll
    for (int mi = 0; mi < 4; mi++)
      af[mi] = *(const s16x8*)(sA + (size_t)(wr * 64 + mi * 16 + rsel) * 32 + ko);
#pragma unroll
    for (int ni = 0; ni < 4; ni++)
      bq[ni] = *(const s16x8*)(sB + (size_t)(wc * 64 + ni * 16 + rsel) * 32 + ko);
#pragma unroll
    for (int mi = 0; mi < 4; mi++)
#pragma unroll
      for (int ni = 0; ni < 4; ni++)
        acc[mi][ni] = __builtin_amdgcn_mfma_f32_16x16x32_bf16(af[mi], bq[ni], acc[mi][ni], 0, 0, 0);
    __syncthreads();
  }

  const int colbase = n0 + wc * 64;
  const int rowbase = m0 + wr * 64;
  if (EPI == 0) {
    float bv[4];
#pragma unroll
    for (int ni = 0; ni < 4; ni++) bv[ni] = bias[(size_t)e * N + colbase + ni * 16 + rsel];
#pragma unroll
    for (int mi = 0; mi < 4; mi++) {
#pragma unroll
      for (int r = 0; r < 4; r++) {
        const int grow = rowbase + mi * 16 + (lane >> 4) * 4 + r;
        if (grow < mlimit) {
          ushort* hrow = Hout + (size_t)grow * N + colbase;
#pragma unroll
          for (int ni = 0; ni < 4; ni++) {
            float v = acc[mi][ni][r] + bv[ni];
            hrow[ni * 16 + rsel] = f2bf(fmaxf(v, 0.0f));
          }
        }
      }
    }
  } else {
    float bv[4];
#pragma unroll
    for (int ni = 0; ni < 4; ni++) bv[ni] = bias[(size_t)e * N + colbase + ni * 16 + rsel];
#pragma unroll
    for (int mi = 0; mi < 4; mi++) {
#pragma unroll
      for (int r = 0; r < 4; r++) {
        const int grow = rowbase + mi * 16 + (lane >> 4) * 4 + r;
        if (grow < mlimit) {
          const int tok = perm[grow];
          const float sc = pmaxArr[tok];
          float* yrow = Y + (size_t)tok * N + colbase;
#pragma unroll
          for (int ni = 0; ni < 4; ni++)
            yrow[ni * 16 + rsel] = (acc[mi][ni][r] + bv[ni]) * sc;
        }
      }
    }
  }
}

// ---------------------------------------------------------------------------
extern "C" void kernel_launch(void* const* d_in, const int* in_sizes, int n_in,
                              void* d_out, int out_size, void* d_ws, size_t ws_size,
                              hipStream_t stream) {
  const float* x  = (const float*)d_in[0];
  const float* sw = (const float*)d_in[1];
  const float* sb = (const float*)d_in[2];
  const float* w1 = (const float*)d_in[3];
  const float* b1 = (const float*)d_in[4];
  const float* w2 = (const float*)d_in[5];
  const float* b2 = (const float*)d_in[6];
  float* out = (float*)d_out;
  float* auxp = out + (size_t)NT * DOUT;

  char* wsb = (char*)d_ws;
  int*   cnt      = (int*)wsb;               // 8 ints
  float* probsum  = (float*)(wsb + 32);      // 8 floats
  int*   offsets  = (int*)(wsb + 64);        // 9 ints
  int*   routes   = (int*)(wsb + 256);
  int*   posArr   = routes + NT;
  float* pmaxArr  = (float*)(posArr + NT);
  int*   perm     = (int*)(pmaxArr + NT);
  ushort* Xg = (ushort*)(wsb + 256 + (size_t)4 * 4 * NT);           // [NT+128][DIN]
  ushort* Hg = Xg + (size_t)(NT + 128) * DIN;                       // [NT+128][DFF]
  ushort* Wt = Hg + (size_t)(NT + 128) * DFF;                       // max(E*DFF*DIN) bf16, reused
  size_t needed = (size_t)(Wt - (ushort*)wsb) * 2 + (size_t)NEXP * DFF * DIN * 2;
  if (ws_size < needed) return;  // insufficient scratch; fail validation visibly

  hipMemsetAsync(d_ws, 0, 64, stream);  // cnt + probsum

  router_kernel<<<NT / 4, 256, 0, stream>>>(x, sw, sb, routes, posArr, pmaxArr, cnt, probsum);
  offsets_aux_kernel<<<1, 64, 0, stream>>>(cnt, probsum, offsets, auxp);
  gather_kernel<<<NT / 4, 256, 0, stream>>>(x, routes, posArr, offsets, perm, Xg);

  // w1: [E][DIN][DFF] -> Wt [E][DFF][DIN]
  transpose_cvt_kernel<<<NEXP * (DIN / 64) * (DFF / 64), 256, 0, stream>>>(w1, Wt, DIN, DFF);
  moe_gemm_kernel<0><<<dim3(DFF / 128, NT / 128, NEXP), 256, 0, stream>>>(
      Xg, Wt, b1, offsets, Hg, nullptr, nullptr, nullptr, DIN, DFF);

  // w2: [E][DFF][DOUT] -> Wt [E][DOUT][DFF]  (reuse Wt; stream-ordered after GEMM1)
  transpose_cvt_kernel<<<NEXP * (DFF / 64) * (DOUT / 64), 256, 0, stream>>>(w2, Wt, DFF, DOUT);
  moe_gemm_kernel<1><<<dim3(DOUT / 128, NT / 128, NEXP), 256, 0, stream>>>(
      Hg, Wt, b2, offsets, nullptr, out, perm, pmaxArr, DFF, DOUT);
}

// Round 2
// 374.954 us; speedup vs baseline: 3.4277x; 3.4277x over previous
//
#include <hip/hip_runtime.h>
#include <cstdint>
#include <cstddef>

#define NT   8192
#define DIN  1024
#define DFF  4096
#define DOUT 1024
#define NEXP 8

typedef float  f32x4v __attribute__((ext_vector_type(4)));
typedef short  s16x8  __attribute__((ext_vector_type(8)));
typedef short  s16x4  __attribute__((ext_vector_type(4)));

__device__ __forceinline__ ushort f2bf(float f) {
  union { float f; uint32_t u; } c; c.f = f;
  uint32_t u = c.u;
  return (ushort)((u + 0x7fffu + ((u >> 16) & 1u)) >> 16);  // RNE
}

// ---------------- router: 1 block = 64 tokens, block-level atomic reduction --
// Wave w handles tokens t0 + w*16 .. t0 + w*16 + 15 (full wave per token).
__global__ __launch_bounds__(256) void router_kernel(
    const float* __restrict__ x, const float* __restrict__ sw,
    const float* __restrict__ sb,
    int* __restrict__ routes, int* __restrict__ posArr,
    float* __restrict__ pmaxArr,
    int* __restrict__ cnt, float* __restrict__ probsum) {
  __shared__ int   sRoute[64];
  __shared__ float sProb[4][NEXP];
  __shared__ int   sBase[NEXP];

  const int lane = threadIdx.x & 63;
  const int w    = threadIdx.x >> 6;
  const int t0   = blockIdx.x * 64;

  float bias[NEXP];
#pragma unroll
  for (int e = 0; e < NEXP; e++) bias[e] = sb[e];

  float wprob[NEXP];
#pragma unroll
  for (int e = 0; e < NEXP; e++) wprob[e] = 0.0f;

  for (int k = 0; k < 16; k++) {
    const int t = t0 + w * 16 + k;
    const float* xr = x + (size_t)t * DIN;
    float acc[NEXP];
#pragma unroll
    for (int e = 0; e < NEXP; e++) acc[e] = 0.0f;
#pragma unroll
    for (int it = 0; it < DIN / 64; it++) {
      const int i = it * 64 + lane;
      const float xv = xr[i];
      const float4 s0 = *(const float4*)(sw + (size_t)i * NEXP);
      const float4 s1 = *(const float4*)(sw + (size_t)i * NEXP + 4);
      acc[0] += xv * s0.x; acc[1] += xv * s0.y; acc[2] += xv * s0.z; acc[3] += xv * s0.w;
      acc[4] += xv * s1.x; acc[5] += xv * s1.y; acc[6] += xv * s1.z; acc[7] += xv * s1.w;
    }
#pragma unroll
    for (int e = 0; e < NEXP; e++) {
#pragma unroll
      for (int off = 32; off > 0; off >>= 1) acc[e] += __shfl_xor(acc[e], off, 64);
    }
    float m = acc[0] + bias[0]; int am = 0;
    float lg[NEXP];
#pragma unroll
    for (int e = 0; e < NEXP; e++) {
      lg[e] = acc[e] + bias[e];
      if (lg[e] > m) { m = lg[e]; am = e; }
    }
    float esum = 0.0f;
    float pe[NEXP];
#pragma unroll
    for (int e = 0; e < NEXP; e++) { pe[e] = __expf(lg[e] - m); esum += pe[e]; }
    const float inv = 1.0f / esum;
#pragma unroll
    for (int e = 0; e < NEXP; e++) wprob[e] += pe[e] * inv;
    if (lane == 0) {
      routes[t] = am;
      pmaxArr[t] = inv;           // pe[am] == 1 -> pmax = 1/esum
      sRoute[w * 16 + k] = am;
    }
  }
  if (lane == 0) {
#pragma unroll
    for (int e = 0; e < NEXP; e++) sProb[w][e] = wprob[e];
  }
  __syncthreads();

  const int tid = threadIdx.x;
  if (tid < NEXP) {
    float s = sProb[0][tid] + sProb[1][tid] + sProb[2][tid] + sProb[3][tid];
    atomicAdd(&probsum[tid], s);
    int c = 0;
#pragma unroll
    for (int j = 0; j < 64; j++) c += (sRoute[j] == tid);
    sBase[tid] = atomicAdd(&cnt[tid], c);
  }
  __syncthreads();

  if (tid < 64) {
    const int r = sRoute[tid];
    int rank = 0;
    for (int j = 0; j < 64; j++) rank += (j < tid) & (sRoute[j] == r);
    posArr[t0 + tid] = sBase[r] + rank;
  }
}

// ---------------- offsets (exclusive scan of 8) + aux loss -------------------
__global__ void offsets_aux_kernel(const int* __restrict__ cnt, const float* __restrict__ probsum,
                                   int* __restrict__ offsets, float* __restrict__ auxout) {
  if (threadIdx.x == 0) {
    int o = 0; float aux = 0.0f;
    for (int e = 0; e < NEXP; e++) {
      offsets[e] = o; o += cnt[e];
      aux += (float)cnt[e] * probsum[e];
    }
    offsets[NEXP] = o;
    auxout[0] = aux * ((float)NEXP / (float)NT);
  }
}

// ---------------- gather tokens into expert-contiguous bf16 rows -------------
__global__ void gather_kernel(const float* __restrict__ x, const int* __restrict__ routes,
                              const int* __restrict__ posArr, const int* __restrict__ offsets,
                              int* __restrict__ perm, ushort* __restrict__ Xg) {
  const int lane = threadIdx.x & 63;
  const int t = (blockIdx.x * blockDim.x + threadIdx.x) >> 6;
  if (t >= NT) return;
  const int slot = offsets[routes[t]] + posArr[t];
  if (lane == 0) perm[slot] = t;
  const float* src = x + (size_t)t * DIN;
  ushort* dst = Xg + (size_t)slot * DIN;
#pragma unroll
  for (int half = 0; half < 2; half++) {
    int i = half * 512 + lane * 8;
    float4 v0 = *(const float4*)(src + i);
    float4 v1 = *(const float4*)(src + i + 4);
    s16x8 p;
    p[0] = (short)f2bf(v0.x); p[1] = (short)f2bf(v0.y);
    p[2] = (short)f2bf(v0.z); p[3] = (short)f2bf(v0.w);
    p[4] = (short)f2bf(v1.x); p[5] = (short)f2bf(v1.y);
    p[6] = (short)f2bf(v1.z); p[7] = (short)f2bf(v1.w);
    *(s16x8*)(dst + i) = p;
  }
}

// ---------------- transpose + fp32->bf16: [E][K][N] -> [E][N][K] -------------
__global__ void transpose_cvt_kernel(const float* __restrict__ src, ushort* __restrict__ dst,
                                     const int K, const int N) {
  __shared__ float tile[64][65];
  const int ntn = N >> 6;
  const int ntk = K >> 6;
  int b = blockIdx.x;
  const int tn = b % ntn; b /= ntn;
  const int tk = b % ntk; const int e = b / ntk;
  const float* s = src + ((size_t)e * K + (size_t)tk * 64) * N + (size_t)tn * 64;
  const int c4 = (threadIdx.x & 15) * 4;
  const int r0 = threadIdx.x >> 4;  // 0..15
#pragma unroll
  for (int p = 0; p < 4; p++) {
    const int row = r0 + p * 16;
    float4 v = *(const float4*)(s + (size_t)row * N + c4);
    tile[row][c4 + 0] = v.x; tile[row][c4 + 1] = v.y;
    tile[row][c4 + 2] = v.z; tile[row][c4 + 3] = v.w;
  }
  __syncthreads();
  ushort* d = dst + ((size_t)e * N + (size_t)tn * 64) * K + (size_t)tk * 64;
#pragma unroll
  for (int p = 0; p < 4; p++) {
    const int nrow = r0 + p * 16;
    s16x4 o;
    o[0] = (short)f2bf(tile[c4 + 0][nrow]);
    o[1] = (short)f2bf(tile[c4 + 1][nrow]);
    o[2] = (short)f2bf(tile[c4 + 2][nrow]);
    o[3] = (short)f2bf(tile[c4 + 3][nrow]);
    *(s16x4*)(d + (size_t)nrow * K + c4) = o;
  }
}

// ---------------- grouped GEMM, 128x128 tile, BK=32, m97-style staging -------
#define GLD16(g, l)                                                                        \
  __builtin_amdgcn_global_load_lds((const __attribute__((address_space(1))) uint32_t*)(g), \
                                   (__attribute__((address_space(3))) uint32_t*)(l), 16, 0, 0)

template <int EPI>
__global__ __launch_bounds__(256) void moe_gemm_kernel(
    const ushort* __restrict__ A,   // [slots][K] bf16, expert-contiguous rows
    const ushort* __restrict__ BT,  // [E][N][K] bf16
    const float* __restrict__ bias, // [E][N]
    const int* __restrict__ offsets,
    ushort* __restrict__ Hout,      // EPI==0: [slots][N] bf16
    float* __restrict__ Y,          // EPI==1: [NT][N] fp32 (scatter)
    const int* __restrict__ perm, const float* __restrict__ pmaxArr,
    const int K, const int N) {
  __shared__ ushort sA[128 * 32];
  __shared__ ushort sB[128 * 32];
  const int e = blockIdx.z;
  const int mlimit = offsets[e + 1];
  const int m0 = offsets[e] + blockIdx.y * 128;
  if (m0 >= mlimit) return;
  const int n0 = blockIdx.x * 128;
  const int tid = threadIdx.x;
  const int lane = tid & 63;
  const int w = tid >> 6;
  const int wr = w >> 1, wc = w & 1;

  const ushort* ga = A + (size_t)(m0 + 32 * w + (lane >> 2)) * K + (size_t)(lane & 3) * 8;
  const ushort* gb = BT + ((size_t)e * N + n0 + 32 * w + (lane >> 2)) * K + (size_t)(lane & 3) * 8;
  ushort* lA = sA + w * 1024;  // chunks 2w, 2w+1 (512 elems = 1KB each)
  ushort* lB = sB + w * 1024;
  const size_t rowstep = (size_t)16 * K;

  f32x4v acc[4][4];
#pragma unroll
  for (int i = 0; i < 4; i++)
#pragma unroll
    for (int j = 0; j < 4; j++) acc[i][j] = (f32x4v)0.0f;

  const int rsel = lane & 15;
  const int ko = (lane >> 4) * 8;

  for (int k0 = 0; k0 < K; k0 += 32) {
    GLD16(ga, lA);
    GLD16(ga + rowstep, lA + 512);
    GLD16(gb, lB);
    GLD16(gb + rowstep, lB + 512);
    ga += 32; gb += 32;
    __syncthreads();
    s16x8 af[4], bq[4];
#pragma unroll
    for (int mi = 0; mi < 4; mi++)
      af[mi] = *(const s16x8*)(sA + (size_t)(wr * 64 + mi * 16 + rsel) * 32 + ko);
#pragma unroll
    for (int ni = 0; ni < 4; ni++)
      bq[ni] = *(const s16x8*)(sB + (size_t)(wc * 64 + ni * 16 + rsel) * 32 + ko);
#pragma unroll
    for (int mi = 0; mi < 4; mi++)
#pragma unroll
      for (int ni = 0; ni < 4; ni++)
        acc[mi][ni] = __builtin_amdgcn_mfma_f32_16x16x32_bf16(af[mi], bq[ni], acc[mi][ni], 0, 0, 0);
    __syncthreads();
  }

  const int colbase = n0 + wc * 64;
  const int rowbase = m0 + wr * 64;
  if (EPI == 0) {
    float bv[4];
#pragma unroll
    for (int ni = 0; ni < 4; ni++) bv[ni] = bias[(size_t)e * N + colbase + ni * 16 + rsel];
#pragma unroll
    for (int mi = 0; mi < 4; mi++) {
#pragma unroll
      for (int r = 0; r < 4; r++) {
        const int grow = rowbase + mi * 16 + (lane >> 4) * 4 + r;
        if (grow < mlimit) {
          ushort* hrow = Hout + (size_t)grow * N + colbase;
#pragma unroll
          for (int ni = 0; ni < 4; ni++) {
            float v = acc[mi][ni][r] + bv[ni];
            hrow[ni * 16 + rsel] = f2bf(fmaxf(v, 0.0f));
          }
        }
      }
    }
  } else {
    float bv[4];
#pragma unroll
    for (int ni = 0; ni < 4; ni++) bv[ni] = bias[(size_t)e * N + colbase + ni * 16 + rsel];
#pragma unroll
    for (int mi = 0; mi < 4; mi++) {
#pragma unroll
      for (int r = 0; r < 4; r++) {
        const int grow = rowbase + mi * 16 + (lane >> 4) * 4 + r;
        if (grow < mlimit) {
          const int tok = perm[grow];
          const float sc = pmaxArr[tok];
          float* yrow = Y + (size_t)tok * N + colbase;
#pragma unroll
          for (int ni = 0; ni < 4; ni++)
            yrow[ni * 16 + rsel] = (acc[mi][ni][r] + bv[ni]) * sc;
        }
      }
    }
  }
}

// ---------------------------------------------------------------------------
extern "C" void kernel_launch(void* const* d_in, const int* in_sizes, int n_in,
                              void* d_out, int out_size, void* d_ws, size_t ws_size,
                              hipStream_t stream) {
  const float* x  = (const float*)d_in[0];
  const float* sw = (const float*)d_in[1];
  const float* sb = (const float*)d_in[2];
  const float* w1 = (const float*)d_in[3];
  const float* b1 = (const float*)d_in[4];
  const float* w2 = (const float*)d_in[5];
  const float* b2 = (const float*)d_in[6];
  float* out = (float*)d_out;
  float* auxp = out + (size_t)NT * DOUT;

  char* wsb = (char*)d_ws;
  int*   cnt      = (int*)wsb;               // 8 ints
  float* probsum  = (float*)(wsb + 32);      // 8 floats
  int*   offsets  = (int*)(wsb + 64);        // 9 ints
  int*   routes   = (int*)(wsb + 256);
  int*   posArr   = routes + NT;
  float* pmaxArr  = (float*)(posArr + NT);
  int*   perm     = (int*)(pmaxArr + NT);
  ushort* Xg = (ushort*)(wsb + 256 + (size_t)4 * 4 * NT);           // [NT+128][DIN]
  ushort* Hg = Xg + (size_t)(NT + 128) * DIN;                       // [NT+128][DFF]
  ushort* Wt = Hg + (size_t)(NT + 128) * DFF;                       // max(E*DFF*DIN) bf16, reused
  size_t needed = (size_t)(Wt - (ushort*)wsb) * 2 + (size_t)NEXP * DFF * DIN * 2;
  if (ws_size < needed) return;  // insufficient scratch; fail validation visibly

  hipMemsetAsync(d_ws, 0, 64, stream);  // cnt + probsum

  router_kernel<<<NT / 64, 256, 0, stream>>>(x, sw, sb, routes, posArr, pmaxArr, cnt, probsum);
  offsets_aux_kernel<<<1, 64, 0, stream>>>(cnt, probsum, offsets, auxp);
  gather_kernel<<<NT / 4, 256, 0, stream>>>(x, routes, posArr, offsets, perm, Xg);

  // w1: [E][DIN][DFF] -> Wt [E][DFF][DIN]
  transpose_cvt_kernel<<<NEXP * (DIN / 64) * (DFF / 64), 256, 0, stream>>>(w1, Wt, DIN, DFF);
  moe_gemm_kernel<0><<<dim3(DFF / 128, NT / 128, NEXP), 256, 0, stream>>>(
      Xg, Wt, b1, offsets, Hg, nullptr, nullptr, nullptr, DIN, DFF);

  // w2: [E][DFF][DOUT] -> Wt [E][DOUT][DFF]  (reuse Wt; stream-ordered after GEMM1)
  transpose_cvt_kernel<<<NEXP * (DFF / 64) * (DOUT / 64), 256, 0, stream>>>(w2, Wt, DFF, DOUT);
  moe_gemm_kernel<1><<<dim3(DOUT / 128, NT / 128, NEXP), 256, 0, stream>>>(
      Hg, Wt, b2, offsets, nullptr, out, perm, pmaxArr, DFF, DOUT);
}

// Round 3
// 371.337 us; speedup vs baseline: 3.4611x; 1.0097x over previous
//
#include <hip/hip_runtime.h>
#include <cstdint>
#include <cstddef>

#define NT   8192
#define DIN  1024
#define DFF  4096
#define DOUT 1024
#define NEXP 8

typedef float  f32x4v __attribute__((ext_vector_type(4)));
typedef short  s16x8  __attribute__((ext_vector_type(8)));
typedef short  s16x4  __attribute__((ext_vector_type(4)));

__device__ __forceinline__ ushort f2bf(float f) {
  union { float f; uint32_t u; } c; c.f = f;
  uint32_t u = c.u;
  return (ushort)((u + 0x7fffu + ((u >> 16) & 1u)) >> 16);  // RNE
}

// ---------------- router: 1 block = 64 tokens, block-level atomic reduction --
__global__ __launch_bounds__(256) void router_kernel(
    const float* __restrict__ x, const float* __restrict__ sw,
    const float* __restrict__ sb,
    int* __restrict__ routes, int* __restrict__ posArr,
    float* __restrict__ pmaxArr,
    int* __restrict__ cnt, float* __restrict__ probsum) {
  __shared__ int   sRoute[64];
  __shared__ float sProb[4][NEXP];
  __shared__ int   sBase[NEXP];

  const int lane = threadIdx.x & 63;
  const int w    = threadIdx.x >> 6;
  const int t0   = blockIdx.x * 64;

  float bias[NEXP];
#pragma unroll
  for (int e = 0; e < NEXP; e++) bias[e] = sb[e];

  float wprob[NEXP];
#pragma unroll
  for (int e = 0; e < NEXP; e++) wprob[e] = 0.0f;

  for (int k = 0; k < 16; k++) {
    const int t = t0 + w * 16 + k;
    const float* xr = x + (size_t)t * DIN;
    float acc[NEXP];
#pragma unroll
    for (int e = 0; e < NEXP; e++) acc[e] = 0.0f;
#pragma unroll
    for (int it = 0; it < DIN / 64; it++) {
      const int i = it * 64 + lane;
      const float xv = xr[i];
      const float4 s0 = *(const float4*)(sw + (size_t)i * NEXP);
      const float4 s1 = *(const float4*)(sw + (size_t)i * NEXP + 4);
      acc[0] += xv * s0.x; acc[1] += xv * s0.y; acc[2] += xv * s0.z; acc[3] += xv * s0.w;
      acc[4] += xv * s1.x; acc[5] += xv * s1.y; acc[6] += xv * s1.z; acc[7] += xv * s1.w;
    }
#pragma unroll
    for (int e = 0; e < NEXP; e++) {
#pragma unroll
      for (int off = 32; off > 0; off >>= 1) acc[e] += __shfl_xor(acc[e], off, 64);
    }
    float m = acc[0] + bias[0]; int am = 0;
    float lg[NEXP];
#pragma unroll
    for (int e = 0; e < NEXP; e++) {
      lg[e] = acc[e] + bias[e];
      if (lg[e] > m) { m = lg[e]; am = e; }
    }
    float esum = 0.0f;
    float pe[NEXP];
#pragma unroll
    for (int e = 0; e < NEXP; e++) { pe[e] = __expf(lg[e] - m); esum += pe[e]; }
    const float inv = 1.0f / esum;
#pragma unroll
    for (int e = 0; e < NEXP; e++) wprob[e] += pe[e] * inv;
    if (lane == 0) {
      routes[t] = am;
      pmaxArr[t] = inv;           // pe[am] == 1 -> pmax = 1/esum
      sRoute[w * 16 + k] = am;
    }
  }
  if (lane == 0) {
#pragma unroll
    for (int e = 0; e < NEXP; e++) sProb[w][e] = wprob[e];
  }
  __syncthreads();

  const int tid = threadIdx.x;
  if (tid < NEXP) {
    float s = sProb[0][tid] + sProb[1][tid] + sProb[2][tid] + sProb[3][tid];
    atomicAdd(&probsum[tid], s);
    int c = 0;
#pragma unroll
    for (int j = 0; j < 64; j++) c += (sRoute[j] == tid);
    sBase[tid] = atomicAdd(&cnt[tid], c);
  }
  __syncthreads();

  if (tid < 64) {
    const int r = sRoute[tid];
    int rank = 0;
    for (int j = 0; j < 64; j++) rank += (j < tid) & (sRoute[j] == r);
    posArr[t0 + tid] = sBase[r] + rank;
  }
}

// ---------------- offsets (exclusive scan of 8) + aux loss -------------------
__global__ void offsets_aux_kernel(const int* __restrict__ cnt, const float* __restrict__ probsum,
                                   int* __restrict__ offsets, float* __restrict__ auxout) {
  if (threadIdx.x == 0) {
    int o = 0; float aux = 0.0f;
    for (int e = 0; e < NEXP; e++) {
      offsets[e] = o; o += cnt[e];
      aux += (float)cnt[e] * probsum[e];
    }
    offsets[NEXP] = o;
    auxout[0] = aux * ((float)NEXP / (float)NT);
  }
}

// ---------------- gather tokens into expert-contiguous bf16 rows -------------
__global__ void gather_kernel(const float* __restrict__ x, const int* __restrict__ routes,
                              const int* __restrict__ posArr, const int* __restrict__ offsets,
                              int* __restrict__ perm, ushort* __restrict__ Xg) {
  const int lane = threadIdx.x & 63;
  const int t = (blockIdx.x * blockDim.x + threadIdx.x) >> 6;
  if (t >= NT) return;
  const int slot = offsets[routes[t]] + posArr[t];
  if (lane == 0) perm[slot] = t;
  const float* src = x + (size_t)t * DIN;
  ushort* dst = Xg + (size_t)slot * DIN;
#pragma unroll
  for (int half = 0; half < 2; half++) {
    int i = half * 512 + lane * 8;
    float4 v0 = *(const float4*)(src + i);
    float4 v1 = *(const float4*)(src + i + 4);
    s16x8 p;
    p[0] = (short)f2bf(v0.x); p[1] = (short)f2bf(v0.y);
    p[2] = (short)f2bf(v0.z); p[3] = (short)f2bf(v0.w);
    p[4] = (short)f2bf(v1.x); p[5] = (short)f2bf(v1.y);
    p[6] = (short)f2bf(v1.z); p[7] = (short)f2bf(v1.w);
    *(s16x8*)(dst + i) = p;
  }
}

// ---------------- transpose + fp32->bf16: [E][K][N] -> [E][N][K] -------------
__global__ void transpose_cvt_kernel(const float* __restrict__ src, ushort* __restrict__ dst,
                                     const int K, const int N) {
  __shared__ float tile[64][65];
  const int ntn = N >> 6;
  const int ntk = K >> 6;
  int b = blockIdx.x;
  const int tn = b % ntn; b /= ntn;
  const int tk = b % ntk; const int e = b / ntk;
  const float* s = src + ((size_t)e * K + (size_t)tk * 64) * N + (size_t)tn * 64;
  const int c4 = (threadIdx.x & 15) * 4;
  const int r0 = threadIdx.x >> 4;  // 0..15
#pragma unroll
  for (int p = 0; p < 4; p++) {
    const int row = r0 + p * 16;
    float4 v = *(const float4*)(s + (size_t)row * N + c4);
    tile[row][c4 + 0] = v.x; tile[row][c4 + 1] = v.y;
    tile[row][c4 + 2] = v.z; tile[row][c4 + 3] = v.w;
  }
  __syncthreads();
  ushort* d = dst + ((size_t)e * N + (size_t)tn * 64) * K + (size_t)tk * 64;
#pragma unroll
  for (int p = 0; p < 4; p++) {
    const int nrow = r0 + p * 16;
    s16x4 o;
    o[0] = (short)f2bf(tile[c4 + 0][nrow]);
    o[1] = (short)f2bf(tile[c4 + 1][nrow]);
    o[2] = (short)f2bf(tile[c4 + 2][nrow]);
    o[3] = (short)f2bf(tile[c4 + 3][nrow]);
    *(s16x4*)(d + (size_t)nrow * K + c4) = o;
  }
}

// ---------------- grouped GEMM, 128x128 tile, BK=32, 2-phase dbuf + swizzle --
#define GLD16(g, l)                                                                        \
  __builtin_amdgcn_global_load_lds((const __attribute__((address_space(1))) uint32_t*)(g), \
                                   (__attribute__((address_space(3))) uint32_t*)(l), 16, 0, 0)

template <int EPI>
__global__ __launch_bounds__(256) void moe_gemm_kernel(
    const ushort* __restrict__ A,   // [slots][K] bf16, expert-contiguous rows
    const ushort* __restrict__ BT,  // [E][N][K] bf16
    const float* __restrict__ bias, // [E][N]
    const int* __restrict__ offsets,
    ushort* __restrict__ Hout,      // EPI==0: [slots][N] bf16
    float* __restrict__ Y,          // EPI==1: [NT][N] fp32 (scatter)
    const int* __restrict__ perm, const float* __restrict__ pmaxArr,
    const int K, const int N) {
  // double-buffered, XOR-swizzled tiles: element (row, kslot s) of buffer b is
  // stored at elem offset  row*32 + (s ^ ((row>>1)&3))*8  (16B granules).
  __shared__ ushort sA[2][128 * 32];
  __shared__ ushort sB[2][128 * 32];
  const int e = blockIdx.z;
  const int mlimit = offsets[e + 1];
  const int m0 = offsets[e] + blockIdx.y * 128;
  if (m0 >= mlimit) return;
  const int n0 = blockIdx.x * 128;
  const int tid = threadIdx.x;
  const int lane = tid & 63;
  const int w = tid >> 6;
  const int wr = w >> 1, wc = w & 1;

  // write side: wave w stages rows 32w+c*16+(lane>>2); LDS dest linear, so the
  // SOURCE k-slot is pre-swizzled: (lane&3) ^ ((row>>1)&3) = (lane&3)^((lane>>3)&3)
  const int srcslot = ((lane & 3) ^ ((lane >> 3) & 3)) * 8;
  const ushort* ga = A + (size_t)(m0 + 32 * w + (lane >> 2)) * K + srcslot;
  const ushort* gb = BT + ((size_t)e * N + n0 + 32 * w + (lane >> 2)) * K + srcslot;
  const size_t rowstep = (size_t)16 * K;

  f32x4v acc[4][4];
#pragma unroll
  for (int i = 0; i < 4; i++)
#pragma unroll
    for (int j = 0; j < 4; j++) acc[i][j] = (f32x4v)0.0f;

  const int rsel = lane & 15;
  // read side: want global k-slot (lane>>4); stored at slot ^ ((row>>1)&3),
  // row parity = rsel parity for both A and B fragments.
  const int sko = (((lane >> 4) ^ ((rsel >> 1) & 3))) * 8;

#define STAGE(b, koff)                                   \
  do {                                                   \
    ushort* lA_ = sA[b] + w * 1024;                      \
    ushort* lB_ = sB[b] + w * 1024;                      \
    GLD16(ga + (koff), lA_);                             \
    GLD16(ga + (koff) + rowstep, lA_ + 512);             \
    GLD16(gb + (koff), lB_);                             \
    GLD16(gb + (koff) + rowstep, lB_ + 512);             \
  } while (0)

#define COMPUTE(b)                                                                   \
  do {                                                                               \
    s16x8 af[4], bq[4];                                                              \
    _Pragma("unroll") for (int mi = 0; mi < 4; mi++)                                 \
        af[mi] = *(const s16x8*)(sA[b] + (size_t)(wr * 64 + mi * 16 + rsel) * 32 + sko); \
    _Pragma("unroll") for (int ni = 0; ni < 4; ni++)                                 \
        bq[ni] = *(const s16x8*)(sB[b] + (size_t)(wc * 64 + ni * 16 + rsel) * 32 + sko); \
    _Pragma("unroll") for (int mi = 0; mi < 4; mi++)                                 \
        _Pragma("unroll") for (int ni = 0; ni < 4; ni++)                             \
            acc[mi][ni] =                                                            \
        __builtin_amdgcn_mfma_f32_16x16x32_bf16(af[mi], bq[ni], acc[mi][ni], 0, 0, 0); \
  } while (0)

  const int NSTEP = K / 32;
  STAGE(0, 0);
  __syncthreads();          // drains vmcnt(0): buf0 ready
  int cur = 0;
  for (int t = 0; t < NSTEP - 1; ++t) {
    STAGE(cur ^ 1, (t + 1) * 32);   // prefetch next tile (overlaps with compute)
    COMPUTE(cur);
    __syncthreads();                // drains vmcnt(0)+lgkmcnt(0): next buf ready
    cur ^= 1;
  }
  COMPUTE(cur);                     // epilogue tile, no barrier needed

#undef STAGE
#undef COMPUTE

  const int colbase = n0 + wc * 64;
  const int rowbase = m0 + wr * 64;
  float bv[4];
#pragma unroll
  for (int ni = 0; ni < 4; ni++) bv[ni] = bias[(size_t)e * N + colbase + ni * 16 + rsel];
  if (EPI == 0) {
#pragma unroll
    for (int mi = 0; mi < 4; mi++) {
#pragma unroll
      for (int r = 0; r < 4; r++) {
        const int grow = rowbase + mi * 16 + (lane >> 4) * 4 + r;
        if (grow < mlimit) {
          ushort* hrow = Hout + (size_t)grow * N + colbase;
#pragma unroll
          for (int ni = 0; ni < 4; ni++) {
            float v = acc[mi][ni][r] + bv[ni];
            hrow[ni * 16 + rsel] = f2bf(fmaxf(v, 0.0f));
          }
        }
      }
    }
  } else {
#pragma unroll
    for (int mi = 0; mi < 4; mi++) {
#pragma unroll
      for (int r = 0; r < 4; r++) {
        const int grow = rowbase + mi * 16 + (lane >> 4) * 4 + r;
        if (grow < mlimit) {
          const int tok = perm[grow];
          const float sc = pmaxArr[tok];
          float* yrow = Y + (size_t)tok * N + colbase;
#pragma unroll
          for (int ni = 0; ni < 4; ni++)
            yrow[ni * 16 + rsel] = (acc[mi][ni][r] + bv[ni]) * sc;
        }
      }
    }
  }
}

// ---------------------------------------------------------------------------
extern "C" void kernel_launch(void* const* d_in, const int* in_sizes, int n_in,
                              void* d_out, int out_size, void* d_ws, size_t ws_size,
                              hipStream_t stream) {
  const float* x  = (const float*)d_in[0];
  const float* sw = (const float*)d_in[1];
  const float* sb = (const float*)d_in[2];
  const float* w1 = (const float*)d_in[3];
  const float* b1 = (const float*)d_in[4];
  const float* w2 = (const float*)d_in[5];
  const float* b2 = (const float*)d_in[6];
  float* out = (float*)d_out;
  float* auxp = out + (size_t)NT * DOUT;

  char* wsb = (char*)d_ws;
  int*   cnt      = (int*)wsb;               // 8 ints
  float* probsum  = (float*)(wsb + 32);      // 8 floats
  int*   offsets  = (int*)(wsb + 64);        // 9 ints
  int*   routes   = (int*)(wsb + 256);
  int*   posArr   = routes + NT;
  float* pmaxArr  = (float*)(posArr + NT);
  int*   perm     = (int*)(pmaxArr + NT);
  ushort* Xg = (ushort*)(wsb + 256 + (size_t)4 * 4 * NT);           // [NT+128][DIN]
  ushort* Hg = Xg + (size_t)(NT + 128) * DIN;                       // [NT+128][DFF]
  ushort* Wt = Hg + (size_t)(NT + 128) * DFF;                       // max(E*DFF*DIN) bf16, reused
  size_t needed = (size_t)(Wt - (ushort*)wsb) * 2 + (size_t)NEXP * DFF * DIN * 2;
  if (ws_size < needed) return;  // insufficient scratch; fail validation visibly

  hipMemsetAsync(d_ws, 0, 64, stream);  // cnt + probsum

  router_kernel<<<NT / 64, 256, 0, stream>>>(x, sw, sb, routes, posArr, pmaxArr, cnt, probsum);
  offsets_aux_kernel<<<1, 64, 0, stream>>>(cnt, probsum, offsets, auxp);
  gather_kernel<<<NT / 4, 256, 0, stream>>>(x, routes, posArr, offsets, perm, Xg);

  // w1: [E][DIN][DFF] -> Wt [E][DFF][DIN]
  transpose_cvt_kernel<<<NEXP * (DIN / 64) * (DFF / 64), 256, 0, stream>>>(w1, Wt, DIN, DFF);
  moe_gemm_kernel<0><<<dim3(DFF / 128, NT / 128, NEXP), 256, 0, stream>>>(
      Xg, Wt, b1, offsets, Hg, nullptr, nullptr, nullptr, DIN, DFF);

  // w2: [E][DFF][DOUT] -> Wt [E][DOUT][DFF]  (reuse Wt; stream-ordered after GEMM1)
  transpose_cvt_kernel<<<NEXP * (DFF / 64) * (DOUT / 64), 256, 0, stream>>>(w2, Wt, DFF, DOUT);
  moe_gemm_kernel<1><<<dim3(DOUT / 128, NT / 128, NEXP), 256, 0, stream>>>(
      Hg, Wt, b2, offsets, nullptr, out, perm, pmaxArr, DFF, DOUT);
}

// Round 4
// 371.206 us; speedup vs baseline: 3.4624x; 1.0004x over previous
//
#include <hip/hip_runtime.h>
#include <cstdint>
#include <cstddef>

#define NT   8192
#define DIN  1024
#define DFF  4096
#define DOUT 1024
#define NEXP 8

typedef float  f32x4v __attribute__((ext_vector_type(4)));
typedef short  s16x8  __attribute__((ext_vector_type(8)));
typedef short  s16x4  __attribute__((ext_vector_type(4)));

__device__ __forceinline__ ushort f2bf(float f) {
  union { float f; uint32_t u; } c; c.f = f;
  uint32_t u = c.u;
  return (ushort)((u + 0x7fffu + ((u >> 16) & 1u)) >> 16);  // RNE
}

// ---------------- router: 1 block = 64 tokens, block-level atomic reduction --
__global__ __launch_bounds__(256) void router_kernel(
    const float* __restrict__ x, const float* __restrict__ sw,
    const float* __restrict__ sb,
    int* __restrict__ routes, int* __restrict__ posArr,
    float* __restrict__ pmaxArr,
    int* __restrict__ cnt, float* __restrict__ probsum) {
  __shared__ int   sRoute[64];
  __shared__ float sProb[4][NEXP];
  __shared__ int   sBase[NEXP];

  const int lane = threadIdx.x & 63;
  const int w    = threadIdx.x >> 6;
  const int t0   = blockIdx.x * 64;

  float bias[NEXP];
#pragma unroll
  for (int e = 0; e < NEXP; e++) bias[e] = sb[e];

  float wprob[NEXP];
#pragma unroll
  for (int e = 0; e < NEXP; e++) wprob[e] = 0.0f;

  for (int k = 0; k < 16; k++) {
    const int t = t0 + w * 16 + k;
    const float* xr = x + (size_t)t * DIN;
    float acc[NEXP];
#pragma unroll
    for (int e = 0; e < NEXP; e++) acc[e] = 0.0f;
#pragma unroll
    for (int it = 0; it < DIN / 64; it++) {
      const int i = it * 64 + lane;
      const float xv = xr[i];
      const float4 s0 = *(const float4*)(sw + (size_t)i * NEXP);
      const float4 s1 = *(const float4*)(sw + (size_t)i * NEXP + 4);
      acc[0] += xv * s0.x; acc[1] += xv * s0.y; acc[2] += xv * s0.z; acc[3] += xv * s0.w;
      acc[4] += xv * s1.x; acc[5] += xv * s1.y; acc[6] += xv * s1.z; acc[7] += xv * s1.w;
    }
#pragma unroll
    for (int e = 0; e < NEXP; e++) {
#pragma unroll
      for (int off = 32; off > 0; off >>= 1) acc[e] += __shfl_xor(acc[e], off, 64);
    }
    float m = acc[0] + bias[0]; int am = 0;
    float lg[NEXP];
#pragma unroll
    for (int e = 0; e < NEXP; e++) {
      lg[e] = acc[e] + bias[e];
      if (lg[e] > m) { m = lg[e]; am = e; }
    }
    float esum = 0.0f;
    float pe[NEXP];
#pragma unroll
    for (int e = 0; e < NEXP; e++) { pe[e] = __expf(lg[e] - m); esum += pe[e]; }
    const float inv = 1.0f / esum;
#pragma unroll
    for (int e = 0; e < NEXP; e++) wprob[e] += pe[e] * inv;
    if (lane == 0) {
      routes[t] = am;
      pmaxArr[t] = inv;           // pe[am] == 1 -> pmax = 1/esum
      sRoute[w * 16 + k] = am;
    }
  }
  if (lane == 0) {
#pragma unroll
    for (int e = 0; e < NEXP; e++) sProb[w][e] = wprob[e];
  }
  __syncthreads();

  const int tid = threadIdx.x;
  if (tid < NEXP) {
    float s = sProb[0][tid] + sProb[1][tid] + sProb[2][tid] + sProb[3][tid];
    atomicAdd(&probsum[tid], s);
    int c = 0;
#pragma unroll
    for (int j = 0; j < 64; j++) c += (sRoute[j] == tid);
    sBase[tid] = atomicAdd(&cnt[tid], c);
  }
  __syncthreads();

  if (tid < 64) {
    const int r = sRoute[tid];
    int rank = 0;
    for (int j = 0; j < 64; j++) rank += (j < tid) & (sRoute[j] == r);
    posArr[t0 + tid] = sBase[r] + rank;
  }
}

// ---------------- offsets (exclusive scan of 8) + aux loss -------------------
__global__ void offsets_aux_kernel(const int* __restrict__ cnt, const float* __restrict__ probsum,
                                   int* __restrict__ offsets, float* __restrict__ auxout) {
  if (threadIdx.x == 0) {
    int o = 0; float aux = 0.0f;
    for (int e = 0; e < NEXP; e++) {
      offsets[e] = o; o += cnt[e];
      aux += (float)cnt[e] * probsum[e];
    }
    offsets[NEXP] = o;
    auxout[0] = aux * ((float)NEXP / (float)NT);
  }
}

// ---------------- gather tokens into expert-contiguous bf16 rows -------------
__global__ void gather_kernel(const float* __restrict__ x, const int* __restrict__ routes,
                              const int* __restrict__ posArr, const int* __restrict__ offsets,
                              int* __restrict__ perm, ushort* __restrict__ Xg) {
  const int lane = threadIdx.x & 63;
  const int t = (blockIdx.x * blockDim.x + threadIdx.x) >> 6;
  if (t >= NT) return;
  const int slot = offsets[routes[t]] + posArr[t];
  if (lane == 0) perm[slot] = t;
  const float* src = x + (size_t)t * DIN;
  ushort* dst = Xg + (size_t)slot * DIN;
#pragma unroll
  for (int half = 0; half < 2; half++) {
    int i = half * 512 + lane * 8;
    float4 v0 = *(const float4*)(src + i);
    float4 v1 = *(const float4*)(src + i + 4);
    s16x8 p;
    p[0] = (short)f2bf(v0.x); p[1] = (short)f2bf(v0.y);
    p[2] = (short)f2bf(v0.z); p[3] = (short)f2bf(v0.w);
    p[4] = (short)f2bf(v1.x); p[5] = (short)f2bf(v1.y);
    p[6] = (short)f2bf(v1.z); p[7] = (short)f2bf(v1.w);
    *(s16x8*)(dst + i) = p;
  }
}

// ---------------- transpose + fp32->bf16: [E][K][N] -> [E][N][K] -------------
__global__ void transpose_cvt_kernel(const float* __restrict__ src, ushort* __restrict__ dst,
                                     const int K, const int N) {
  __shared__ float tile[64][65];
  const int ntn = N >> 6;
  const int ntk = K >> 6;
  int b = blockIdx.x;
  const int tn = b % ntn; b /= ntn;
  const int tk = b % ntk; const int e = b / ntk;
  const float* s = src + ((size_t)e * K + (size_t)tk * 64) * N + (size_t)tn * 64;
  const int c4 = (threadIdx.x & 15) * 4;
  const int r0 = threadIdx.x >> 4;  // 0..15
#pragma unroll
  for (int p = 0; p < 4; p++) {
    const int row = r0 + p * 16;
    float4 v = *(const float4*)(s + (size_t)row * N + c4);
    tile[row][c4 + 0] = v.x; tile[row][c4 + 1] = v.y;
    tile[row][c4 + 2] = v.z; tile[row][c4 + 3] = v.w;
  }
  __syncthreads();
  ushort* d = dst + ((size_t)e * N + (size_t)tn * 64) * K + (size_t)tk * 64;
#pragma unroll
  for (int p = 0; p < 4; p++) {
    const int nrow = r0 + p * 16;
    s16x4 o;
    o[0] = (short)f2bf(tile[c4 + 0][nrow]);
    o[1] = (short)f2bf(tile[c4 + 1][nrow]);
    o[2] = (short)f2bf(tile[c4 + 2][nrow]);
    o[3] = (short)f2bf(tile[c4 + 3][nrow]);
    *(s16x4*)(d + (size_t)nrow * K + c4) = o;
  }
}

#define GLD16(g, l)                                                                        \
  __builtin_amdgcn_global_load_lds((const __attribute__((address_space(1))) uint32_t*)(g), \
                                   (__attribute__((address_space(3))) uint32_t*)(l), 16, 0, 0)

#define SBAR()   asm volatile("s_barrier" ::: "memory")
#define WAITV(n) asm volatile("s_waitcnt vmcnt(" #n ")" ::: "memory")

// ============ 256x256 / BK=64 / 8-wave / 8-phase grouped GEMM (GEMM1) ========
// LDS: per operand a ring of 4 half-tile slots (128 rows x 64 k, bf16 = 16KB).
// Tile t uses slots (2t)&3 (half0 = rows 0-127) and (2t+1)&3 (half1).
// Swizzle: element (row, kslot) stored at phys kslot ^ (row&7)  (16B granules);
// staged via pre-swizzled GLOBAL source with linear LDS dest (rule #21).
// Phases per K-tile: q0=(mg0,ng0) q1=(mg0,ng1) q2=(mg1,ng1) q3=(mg1,ng0);
// stage schedule (tile t+1): A0@q0, B0@q1, B1@q2, A1@q3; waits vmcnt(4) at
// q0/q1/q3 ends (3-phase prefetch lead, never 0 in steady state).
template <int KDIM>
__global__ __launch_bounds__(512, 2) void moe_gemm256_kernel(
    const ushort* __restrict__ A,   // [slots][K] bf16 expert-contiguous
    const ushort* __restrict__ BT,  // [E][N][K] bf16
    const float* __restrict__ bias, // [E][N]
    const int* __restrict__ offsets,
    ushort* __restrict__ Hout,      // [slots][N] bf16 (relu)
    const int N) {
  __shared__ ushort sA[4][8192];
  __shared__ ushort sB[4][8192];
  const int e = blockIdx.z;
  const int mlimit = offsets[e + 1];
  const int m0 = offsets[e] + blockIdx.y * 256;
  if (m0 >= mlimit) return;
  const int n0 = blockIdx.x * 256;
  const int tid = threadIdx.x;
  const int lane = tid & 63;
  const int wid = tid >> 6;
  const int wr = wid >> 2;   // 0..1 : row 64-group within each 128-half
  const int wc = wid & 3;    // 0..3 : col 32-group within each 128-half
  const int rsel = lane & 15;
  const int lhi = lane >> 4; // 0..3

  // staging: thread covers LDS bytes tid*16 (+8192) of a 16KB half-tile.
  const int srow = wid * 8 + (lane >> 3);           // row_local for chunk 0
  const int scol = ((lane & 7) ^ (lane >> 3)) * 8;  // pre-swizzled source col
  const ushort* gA = A + (size_t)(m0 + srow) * KDIM + scol;
  const ushort* gB = BT + ((size_t)e * N + n0 + srow) * KDIM + scol;
  const int ldst = tid * 8;  // elem offset; +4096 for chunk 1 (rows +64)

#define STAGE_A(s, h, kt)                                              \
  do {                                                                 \
    const ushort* g_ = gA + (size_t)((h) * 128 + (kt) == (kt) ? 0 : 0, \
                                     (size_t)((h) * 128)) * KDIM +     \
                       (size_t)(kt) * 64;                              \
    GLD16(g_, &sA[s][ldst]);                                           \
    GLD16(g_ + (size_t)64 * KDIM, &sA[s][ldst + 4096]);                \
  } while (0)
#undef STAGE_A
#define STAGE_A(s, h, kt)                                                          \
  do {                                                                             \
    const ushort* g_ = gA + (size_t)((h) * 128) * KDIM + (size_t)(kt) * 64;        \
    GLD16(g_, &sA[s][ldst]);                                                       \
    GLD16(g_ + (size_t)64 * KDIM, &sA[s][ldst + 4096]);                            \
  } while (0)
#define STAGE_B(s, h, kt)                                                          \
  do {                                                                             \
    const ushort* g_ = gB + (size_t)((h) * 128) * KDIM + (size_t)(kt) * 64;        \
    GLD16(g_, &sB[s][ldst]);                                                       \
    GLD16(g_ + (size_t)64 * KDIM, &sB[s][ldst + 4096]);                            \
  } while (0)

  f32x4v acc[2][2][4][2];
#pragma unroll
  for (int i = 0; i < 2; i++)
#pragma unroll
    for (int j = 0; j < 2; j++)
#pragma unroll
      for (int mf = 0; mf < 4; mf++)
#pragma unroll
        for (int nf = 0; nf < 2; nf++) acc[i][j][mf][nf] = (f32x4v)0.0f;

  const int rsw = rsel & 7;
  const int sw0 = ((lhi) ^ rsw) * 8;       // phys 16B-slot for k-step 0
  const int sw1 = ((4 + lhi) ^ rsw) * 8;   // phys 16B-slot for k-step 1
  int arow[4], brow[2];
#pragma unroll
  for (int mf = 0; mf < 4; mf++) arow[mf] = (wr * 64 + mf * 16 + rsel) * 64;
#pragma unroll
  for (int nf = 0; nf < 2; nf++) brow[nf] = (wc * 32 + nf * 16 + rsel) * 64;

  s16x8 a[4][2], b0[2][2], b1[2][2];

#define LDA(slot)                                                      \
  do {                                                                 \
    _Pragma("unroll") for (int mf = 0; mf < 4; mf++) {                 \
      a[mf][0] = *(const s16x8*)&sA[slot][arow[mf] + sw0];             \
      a[mf][1] = *(const s16x8*)&sA[slot][arow[mf] + sw1];             \
    }                                                                  \
  } while (0)
#define LDB(dst, slot)                                                 \
  do {                                                                 \
    _Pragma("unroll") for (int nf = 0; nf < 2; nf++) {                 \
      dst[nf][0] = *(const s16x8*)&sB[slot][brow[nf] + sw0];           \
      dst[nf][1] = *(const s16x8*)&sB[slot][brow[nf] + sw1];           \
    }                                                                  \
  } while (0)
#define MFMAQ(MG, NG, BB)                                              \
  do {                                                                 \
    __builtin_amdgcn_s_setprio(1);                                     \
    _Pragma("unroll") for (int mf = 0; mf < 4; mf++)                   \
    _Pragma("unroll") for (int nf = 0; nf < 2; nf++)                   \
    _Pragma("unroll") for (int ks = 0; ks < 2; ks++)                   \
      acc[MG][NG][mf][nf] = __builtin_amdgcn_mfma_f32_16x16x32_bf16(   \
          a[mf][ks], BB[nf][ks], acc[MG][NG][mf][nf], 0, 0, 0);        \
    __builtin_amdgcn_s_setprio(0);                                     \
  } while (0)

  constexpr int NS = KDIM / 64;
  // prologue: stage tile 0 in consumption-need order A0,B0,B1,A1
  STAGE_A(0, 0, 0);
  STAGE_B(0, 0, 0);
  STAGE_B(1, 1, 0);
  STAGE_A(1, 1, 0);
  WAITV(4);   // A0,B0 landed (B1,A1 may fly; needed later)
  SBAR();

#pragma unroll 2
  for (int t = 0; t < NS; ++t) {
    const int s0 = (2 * t) & 3, s1 = (2 * t + 1) & 3;
    const int sn0 = (2 * t + 2) & 3, sn1 = (2 * t + 3) & 3;
    const bool more = (t + 1 < NS);
    // ---- q0: (mg0, ng0) — reads A-half0, B-half0
    LDA(s0);
    LDB(b0, s0);
    if (more) STAGE_A(sn0, 0, t + 1);
    SBAR();
    MFMAQ(0, 0, b0);
    if (more) { WAITV(4); } else { WAITV(2); }  // ensure B1(t) landed
    SBAR();
    // ---- q1: (mg0, ng1) — reads B-half1
    LDB(b1, s1);
    if (more) STAGE_B(sn0, 0, t + 1);
    SBAR();
    MFMAQ(0, 1, b1);
    if (more) { WAITV(4); } else { WAITV(0); }  // ensure A1(t) landed
    SBAR();
    // ---- q2: (mg1, ng1) — reads A-half1
    LDA(s1);
    if (more) STAGE_B(sn1, 1, t + 1);
    SBAR();
    MFMAQ(1, 1, b1);
    SBAR();
    // ---- q3: (mg1, ng0) — pure reuse
    if (more) STAGE_A(sn1, 1, t + 1);
    SBAR();
    MFMAQ(1, 0, b0);
    if (more) { WAITV(4); }  // ensure A0(t+1),B0(t+1) landed
    SBAR();
  }
#undef LDA
#undef LDB
#undef MFMAQ
#undef STAGE_A
#undef STAGE_B

  // epilogue: bias + relu + bf16 store
  float bv[2][2];
#pragma unroll
  for (int ng = 0; ng < 2; ng++)
#pragma unroll
    for (int nf = 0; nf < 2; nf++)
      bv[ng][nf] = bias[(size_t)e * N + n0 + ng * 128 + wc * 32 + nf * 16 + rsel];
#pragma unroll
  for (int mg = 0; mg < 2; mg++) {
#pragma unroll
    for (int mf = 0; mf < 4; mf++) {
#pragma unroll
      for (int r = 0; r < 4; r++) {
        const int grow = m0 + mg * 128 + wr * 64 + mf * 16 + lhi * 4 + r;
        if (grow < mlimit) {
          ushort* hrow = Hout + (size_t)grow * N + n0;
#pragma unroll
          for (int ng = 0; ng < 2; ng++)
#pragma unroll
            for (int nf = 0; nf < 2; nf++) {
              float v = acc[mg][ng][mf][nf][r] + bv[ng][nf];
              hrow[ng * 128 + wc * 32 + nf * 16 + rsel] = f2bf(fmaxf(v, 0.0f));
            }
        }
      }
    }
  }
}

// ---------------- grouped GEMM, 128x128 tile, BK=32, 2-phase dbuf (GEMM2) ----
template <int EPI>
__global__ __launch_bounds__(256) void moe_gemm_kernel(
    const ushort* __restrict__ A, const ushort* __restrict__ BT,
    const float* __restrict__ bias, const int* __restrict__ offsets,
    ushort* __restrict__ Hout, float* __restrict__ Y,
    const int* __restrict__ perm, const float* __restrict__ pmaxArr,
    const int K, const int N) {
  __shared__ ushort sA[2][128 * 32];
  __shared__ ushort sB[2][128 * 32];
  const int e = blockIdx.z;
  const int mlimit = offsets[e + 1];
  const int m0 = offsets[e] + blockIdx.y * 128;
  if (m0 >= mlimit) return;
  const int n0 = blockIdx.x * 128;
  const int tid = threadIdx.x;
  const int lane = tid & 63;
  const int w = tid >> 6;
  const int wr = w >> 1, wc = w & 1;

  const int srcslot = ((lane & 3) ^ ((lane >> 3) & 3)) * 8;
  const ushort* ga = A + (size_t)(m0 + 32 * w + (lane >> 2)) * K + srcslot;
  const ushort* gb = BT + ((size_t)e * N + n0 + 32 * w + (lane >> 2)) * K + srcslot;
  const size_t rowstep = (size_t)16 * K;

  f32x4v acc[4][4];
#pragma unroll
  for (int i = 0; i < 4; i++)
#pragma unroll
    for (int j = 0; j < 4; j++) acc[i][j] = (f32x4v)0.0f;

  const int rsel = lane & 15;
  const int sko = (((lane >> 4) ^ ((rsel >> 1) & 3))) * 8;

#define STAGE(b, koff)                                   \
  do {                                                   \
    ushort* lA_ = sA[b] + w * 1024;                      \
    ushort* lB_ = sB[b] + w * 1024;                      \
    GLD16(ga + (koff), lA_);                             \
    GLD16(ga + (koff) + rowstep, lA_ + 512);             \
    GLD16(gb + (koff), lB_);                             \
    GLD16(gb + (koff) + rowstep, lB_ + 512);             \
  } while (0)

#define COMPUTE(b)                                                                   \
  do {                                                                               \
    s16x8 af[4], bq[4];                                                              \
    _Pragma("unroll") for (int mi = 0; mi < 4; mi++)                                 \
        af[mi] = *(const s16x8*)(sA[b] + (size_t)(wr * 64 + mi * 16 + rsel) * 32 + sko); \
    _Pragma("unroll") for (int ni = 0; ni < 4; ni++)                                 \
        bq[ni] = *(const s16x8*)(sB[b] + (size_t)(wc * 64 + ni * 16 + rsel) * 32 + sko); \
    _Pragma("unroll") for (int mi = 0; mi < 4; mi++)                                 \
        _Pragma("unroll") for (int ni = 0; ni < 4; ni++)                             \
            acc[mi][ni] =                                                            \
        __builtin_amdgcn_mfma_f32_16x16x32_bf16(af[mi], bq[ni], acc[mi][ni], 0, 0, 0); \
  } while (0)

  const int NSTEP = K / 32;
  STAGE(0, 0);
  __syncthreads();
  int cur = 0;
  for (int t = 0; t < NSTEP - 1; ++t) {
    STAGE(cur ^ 1, (t + 1) * 32);
    COMPUTE(cur);
    __syncthreads();
    cur ^= 1;
  }
  COMPUTE(cur);

#undef STAGE
#undef COMPUTE

  const int colbase = n0 + wc * 64;
  const int rowbase = m0 + wr * 64;
  float bv[4];
#pragma unroll
  for (int ni = 0; ni < 4; ni++) bv[ni] = bias[(size_t)e * N + colbase + ni * 16 + rsel];
  if (EPI == 0) {
#pragma unroll
    for (int mi = 0; mi < 4; mi++) {
#pragma unroll
      for (int r = 0; r < 4; r++) {
        const int grow = rowbase + mi * 16 + (lane >> 4) * 4 + r;
        if (grow < mlimit) {
          ushort* hrow = Hout + (size_t)grow * N + colbase;
#pragma unroll
          for (int ni = 0; ni < 4; ni++) {
            float v = acc[mi][ni][r] + bv[ni];
            hrow[ni * 16 + rsel] = f2bf(fmaxf(v, 0.0f));
          }
        }
      }
    }
  } else {
#pragma unroll
    for (int mi = 0; mi < 4; mi++) {
#pragma unroll
      for (int r = 0; r < 4; r++) {
        const int grow = rowbase + mi * 16 + (lane >> 4) * 4 + r;
        if (grow < mlimit) {
          const int tok = perm[grow];
          const float sc = pmaxArr[tok];
          float* yrow = Y + (size_t)tok * N + colbase;
#pragma unroll
          for (int ni = 0; ni < 4; ni++)
            yrow[ni * 16 + rsel] = (acc[mi][ni][r] + bv[ni]) * sc;
        }
      }
    }
  }
}

// ---------------------------------------------------------------------------
extern "C" void kernel_launch(void* const* d_in, const int* in_sizes, int n_in,
                              void* d_out, int out_size, void* d_ws, size_t ws_size,
                              hipStream_t stream) {
  const float* x  = (const float*)d_in[0];
  const float* sw = (const float*)d_in[1];
  const float* sb = (const float*)d_in[2];
  const float* w1 = (const float*)d_in[3];
  const float* b1 = (const float*)d_in[4];
  const float* w2 = (const float*)d_in[5];
  const float* b2 = (const float*)d_in[6];
  float* out = (float*)d_out;
  float* auxp = out + (size_t)NT * DOUT;

  char* wsb = (char*)d_ws;
  int*   cnt      = (int*)wsb;               // 8 ints
  float* probsum  = (float*)(wsb + 32);      // 8 floats
  int*   offsets  = (int*)(wsb + 64);        // 9 ints
  int*   routes   = (int*)(wsb + 256);
  int*   posArr   = routes + NT;
  float* pmaxArr  = (float*)(posArr + NT);
  int*   perm     = (int*)(pmaxArr + NT);
  ushort* Xg = (ushort*)(wsb + 256 + (size_t)4 * 4 * NT);           // [NT+256][DIN]
  ushort* Hg = Xg + (size_t)(NT + 256) * DIN;                       // [NT+256][DFF]
  ushort* Wt = Hg + (size_t)(NT + 256) * DFF;                       // E*DFF*DIN bf16, reused
  size_t needed = (size_t)((char*)Wt - wsb) + (size_t)NEXP * DFF * DIN * 2;
  if (ws_size < needed) return;  // insufficient scratch; fail validation visibly

  hipMemsetAsync(d_ws, 0, 64, stream);  // cnt + probsum

  router_kernel<<<NT / 64, 256, 0, stream>>>(x, sw, sb, routes, posArr, pmaxArr, cnt, probsum);
  offsets_aux_kernel<<<1, 64, 0, stream>>>(cnt, probsum, offsets, auxp);
  gather_kernel<<<NT / 4, 256, 0, stream>>>(x, routes, posArr, offsets, perm, Xg);

  // w1: [E][DIN][DFF] -> Wt [E][DFF][DIN]
  transpose_cvt_kernel<<<NEXP * (DIN / 64) * (DFF / 64), 256, 0, stream>>>(w1, Wt, DIN, DFF);
  // GEMM1: 256x256 8-phase. grid.y=8 covers cnt_e <= 2048 (>17 sigma of the
  // multinomial; cnt ~ 1024 +- 30).
  moe_gemm256_kernel<DIN><<<dim3(DFF / 256, 8, NEXP), 512, 0, stream>>>(
      Xg, Wt, b1, offsets, Hg, DFF);

  // w2: [E][DFF][DOUT] -> Wt [E][DOUT][DFF]  (reuse Wt; stream-ordered)
  transpose_cvt_kernel<<<NEXP * (DFF / 64) * (DOUT / 64), 256, 0, stream>>>(w2, Wt, DFF, DOUT);
  moe_gemm_kernel<1><<<dim3(DOUT / 128, 16, NEXP), 256, 0, stream>>>(
      Hg, Wt, b2, offsets, nullptr, out, perm, pmaxArr, DFF, DOUT);
}

// Round 5
// 356.194 us; speedup vs baseline: 3.6083x; 1.0421x over previous
//
#include <hip/hip_runtime.h>
#include <cstdint>
#include <cstddef>

#define NT   8192
#define DIN  1024
#define DFF  4096
#define DOUT 1024
#define NEXP 8

typedef float  f32x4v __attribute__((ext_vector_type(4)));
typedef short  s16x8  __attribute__((ext_vector_type(8)));
typedef short  s16x4  __attribute__((ext_vector_type(4)));

__device__ __forceinline__ ushort f2bf(float f) {
  union { float f; uint32_t u; } c; c.f = f;
  uint32_t u = c.u;
  return (ushort)((u + 0x7fffu + ((u >> 16) & 1u)) >> 16);  // RNE
}

// ---------------- router: 1 block = 64 tokens, block-level atomic reduction --
__global__ __launch_bounds__(256) void router_kernel(
    const float* __restrict__ x, const float* __restrict__ sw,
    const float* __restrict__ sb,
    int* __restrict__ routes, int* __restrict__ posArr,
    float* __restrict__ pmaxArr,
    int* __restrict__ cnt, float* __restrict__ probsum) {
  __shared__ int   sRoute[64];
  __shared__ float sProb[4][NEXP];
  __shared__ int   sBase[NEXP];

  const int lane = threadIdx.x & 63;
  const int w    = threadIdx.x >> 6;
  const int t0   = blockIdx.x * 64;

  float bias[NEXP];
#pragma unroll
  for (int e = 0; e < NEXP; e++) bias[e] = sb[e];

  float wprob[NEXP];
#pragma unroll
  for (int e = 0; e < NEXP; e++) wprob[e] = 0.0f;

  for (int k = 0; k < 16; k++) {
    const int t = t0 + w * 16 + k;
    const float* xr = x + (size_t)t * DIN;
    float acc[NEXP];
#pragma unroll
    for (int e = 0; e < NEXP; e++) acc[e] = 0.0f;
#pragma unroll
    for (int it = 0; it < DIN / 64; it++) {
      const int i = it * 64 + lane;
      const float xv = xr[i];
      const float4 s0 = *(const float4*)(sw + (size_t)i * NEXP);
      const float4 s1 = *(const float4*)(sw + (size_t)i * NEXP + 4);
      acc[0] += xv * s0.x; acc[1] += xv * s0.y; acc[2] += xv * s0.z; acc[3] += xv * s0.w;
      acc[4] += xv * s1.x; acc[5] += xv * s1.y; acc[6] += xv * s1.z; acc[7] += xv * s1.w;
    }
#pragma unroll
    for (int e = 0; e < NEXP; e++) {
#pragma unroll
      for (int off = 32; off > 0; off >>= 1) acc[e] += __shfl_xor(acc[e], off, 64);
    }
    float m = acc[0] + bias[0]; int am = 0;
    float lg[NEXP];
#pragma unroll
    for (int e = 0; e < NEXP; e++) {
      lg[e] = acc[e] + bias[e];
      if (lg[e] > m) { m = lg[e]; am = e; }
    }
    float esum = 0.0f;
    float pe[NEXP];
#pragma unroll
    for (int e = 0; e < NEXP; e++) { pe[e] = __expf(lg[e] - m); esum += pe[e]; }
    const float inv = 1.0f / esum;
#pragma unroll
    for (int e = 0; e < NEXP; e++) wprob[e] += pe[e] * inv;
    if (lane == 0) {
      routes[t] = am;
      pmaxArr[t] = inv;           // pe[am] == 1 -> pmax = 1/esum
      sRoute[w * 16 + k] = am;
    }
  }
  if (lane == 0) {
#pragma unroll
    for (int e = 0; e < NEXP; e++) sProb[w][e] = wprob[e];
  }
  __syncthreads();

  const int tid = threadIdx.x;
  if (tid < NEXP) {
    float s = sProb[0][tid] + sProb[1][tid] + sProb[2][tid] + sProb[3][tid];
    atomicAdd(&probsum[tid], s);
    int c = 0;
#pragma unroll
    for (int j = 0; j < 64; j++) c += (sRoute[j] == tid);
    sBase[tid] = atomicAdd(&cnt[tid], c);
  }
  __syncthreads();

  if (tid < 64) {
    const int r = sRoute[tid];
    int rank = 0;
    for (int j = 0; j < 64; j++) rank += (j < tid) & (sRoute[j] == r);
    posArr[t0 + tid] = sBase[r] + rank;
  }
}

// ---------------- offsets (exclusive scan of 8) + aux loss -------------------
__global__ void offsets_aux_kernel(const int* __restrict__ cnt, const float* __restrict__ probsum,
                                   int* __restrict__ offsets, float* __restrict__ auxout) {
  if (threadIdx.x == 0) {
    int o = 0; float aux = 0.0f;
    for (int e = 0; e < NEXP; e++) {
      offsets[e] = o; o += cnt[e];
      aux += (float)cnt[e] * probsum[e];
    }
    offsets[NEXP] = o;
    auxout[0] = aux * ((float)NEXP / (float)NT);
  }
}

// ---------------- gather tokens into expert-contiguous bf16 rows -------------
__global__ void gather_kernel(const float* __restrict__ x, const int* __restrict__ routes,
                              const int* __restrict__ posArr, const int* __restrict__ offsets,
                              int* __restrict__ perm, ushort* __restrict__ Xg) {
  const int lane = threadIdx.x & 63;
  const int t = (blockIdx.x * blockDim.x + threadIdx.x) >> 6;
  if (t >= NT) return;
  const int slot = offsets[routes[t]] + posArr[t];
  if (lane == 0) perm[slot] = t;
  const float* src = x + (size_t)t * DIN;
  ushort* dst = Xg + (size_t)slot * DIN;
#pragma unroll
  for (int half = 0; half < 2; half++) {
    int i = half * 512 + lane * 8;
    float4 v0 = *(const float4*)(src + i);
    float4 v1 = *(const float4*)(src + i + 4);
    s16x8 p;
    p[0] = (short)f2bf(v0.x); p[1] = (short)f2bf(v0.y);
    p[2] = (short)f2bf(v0.z); p[3] = (short)f2bf(v0.w);
    p[4] = (short)f2bf(v1.x); p[5] = (short)f2bf(v1.y);
    p[6] = (short)f2bf(v1.z); p[7] = (short)f2bf(v1.w);
    *(s16x8*)(dst + i) = p;
  }
}

// ---------------- transpose + fp32->bf16: [E][K][N] -> [E][N][K] -------------
__global__ void transpose_cvt_kernel(const float* __restrict__ src, ushort* __restrict__ dst,
                                     const int K, const int N) {
  __shared__ float tile[64][65];
  const int ntn = N >> 6;
  const int ntk = K >> 6;
  int b = blockIdx.x;
  const int tn = b % ntn; b /= ntn;
  const int tk = b % ntk; const int e = b / ntk;
  const float* s = src + ((size_t)e * K + (size_t)tk * 64) * N + (size_t)tn * 64;
  const int c4 = (threadIdx.x & 15) * 4;
  const int r0 = threadIdx.x >> 4;  // 0..15
#pragma unroll
  for (int p = 0; p < 4; p++) {
    const int row = r0 + p * 16;
    float4 v = *(const float4*)(s + (size_t)row * N + c4);
    tile[row][c4 + 0] = v.x; tile[row][c4 + 1] = v.y;
    tile[row][c4 + 2] = v.z; tile[row][c4 + 3] = v.w;
  }
  __syncthreads();
  ushort* d = dst + ((size_t)e * N + (size_t)tn * 64) * K + (size_t)tk * 64;
#pragma unroll
  for (int p = 0; p < 4; p++) {
    const int nrow = r0 + p * 16;
    s16x4 o;
    o[0] = (short)f2bf(tile[c4 + 0][nrow]);
    o[1] = (short)f2bf(tile[c4 + 1][nrow]);
    o[2] = (short)f2bf(tile[c4 + 2][nrow]);
    o[3] = (short)f2bf(tile[c4 + 3][nrow]);
    *(s16x4*)(d + (size_t)nrow * K + c4) = o;
  }
}

#define GLD16(g, l)                                                                        \
  __builtin_amdgcn_global_load_lds((const __attribute__((address_space(1))) uint32_t*)(g), \
                                   (__attribute__((address_space(3))) uint32_t*)(l), 16, 0, 0)

#define SBAR()   asm volatile("s_barrier" ::: "memory")
#define WAITV(n) asm volatile("s_waitcnt vmcnt(" #n ")" ::: "memory")

// ============ 256x256 / BK=64 / 8-wave / 8-phase grouped GEMM ================
// LDS: per operand a ring of 4 half-tile slots (128 rows x 64 k, bf16 = 16KB).
// Tile t uses slots (2t)&3 (half0 = rows 0-127) and (2t+1)&3 (half1).
// Swizzle: element (row, kslot) stored at phys kslot ^ (row&7) (16B granules);
// staged via pre-swizzled GLOBAL source with linear LDS dest (rule #21).
// Phases per K-tile: q0=(mg0,ng0) q1=(mg0,ng1) q2=(mg1,ng1) q3=(mg1,ng0);
// stage schedule (tile t+1): A0@q0, B0@q1, B1@q2, A1@q3; waits vmcnt(4) at
// q0/q1/q3 ends (3-4 phase prefetch lead, never 0 in steady state).
// NOTE: launch_bounds min-waves/EU MUST be 1: live state is ~180 VGPR
// (acc 64 + a 32 + b 32 + addr); ",2" would cap at 128 VGPR -> acc spills
// in the MFMA loop (R3's silent perf bug).
template <int KDIM, int EPI>
__global__ __launch_bounds__(512, 1) void moe_gemm256_kernel(
    const ushort* __restrict__ A,   // [slots][K] bf16 expert-contiguous
    const ushort* __restrict__ BT,  // [E][N][K] bf16
    const float* __restrict__ bias, // [E][N]
    const int* __restrict__ offsets,
    ushort* __restrict__ Hout,      // EPI==0: [slots][N] bf16 (relu)
    float* __restrict__ Y,          // EPI==1: [NT][N] fp32 scatter
    const int* __restrict__ perm, const float* __restrict__ pmaxArr,
    const int N) {
  __shared__ ushort sA[4][8192];
  __shared__ ushort sB[4][8192];
  const int e = blockIdx.z;
  const int mlimit = offsets[e + 1];
  const int m0 = offsets[e] + blockIdx.y * 256;
  if (m0 >= mlimit) return;
  const int n0 = blockIdx.x * 256;
  const int tid = threadIdx.x;
  const int lane = tid & 63;
  const int wid = tid >> 6;
  const int wr = wid >> 2;   // 0..1 : row 64-group within each 128-half
  const int wc = wid & 3;    // 0..3 : col 32-group within each 128-half
  const int rsel = lane & 15;
  const int lhi = lane >> 4; // 0..3

  // staging: thread covers LDS bytes tid*16 (+8192B) of a 16KB half-tile.
  const int srow = wid * 8 + (lane >> 3);           // row_local for chunk 0
  const int scol = ((lane & 7) ^ (lane >> 3)) * 8;  // pre-swizzled source col
  const ushort* gA = A + (size_t)(m0 + srow) * KDIM + scol;
  const ushort* gB = BT + ((size_t)e * N + n0 + srow) * KDIM + scol;
  const int ldst = tid * 8;  // elem offset; +4096 for chunk 1 (rows +64)

#define STAGE_A(s, h, kt)                                                   \
  do {                                                                      \
    const ushort* g_ = gA + (size_t)((h) * 128) * KDIM + (size_t)(kt) * 64; \
    GLD16(g_, &sA[s][ldst]);                                                \
    GLD16(g_ + (size_t)64 * KDIM, &sA[s][ldst + 4096]);                     \
  } while (0)
#define STAGE_B(s, h, kt)                                                   \
  do {                                                                      \
    const ushort* g_ = gB + (size_t)((h) * 128) * KDIM + (size_t)(kt) * 64; \
    GLD16(g_, &sB[s][ldst]);                                                \
    GLD16(g_ + (size_t)64 * KDIM, &sB[s][ldst + 4096]);                     \
  } while (0)

  f32x4v acc[2][2][4][2];
#pragma unroll
  for (int i = 0; i < 2; i++)
#pragma unroll
    for (int j = 0; j < 2; j++)
#pragma unroll
      for (int mf = 0; mf < 4; mf++)
#pragma unroll
        for (int nf = 0; nf < 2; nf++) acc[i][j][mf][nf] = (f32x4v)0.0f;

  const int rsw = rsel & 7;
  const int sw0 = ((lhi) ^ rsw) * 8;       // phys 16B-slot for k-step 0
  const int sw1 = ((4 + lhi) ^ rsw) * 8;   // phys 16B-slot for k-step 1
  int arow[4], brow[2];
#pragma unroll
  for (int mf = 0; mf < 4; mf++) arow[mf] = (wr * 64 + mf * 16 + rsel) * 64;
#pragma unroll
  for (int nf = 0; nf < 2; nf++) brow[nf] = (wc * 32 + nf * 16 + rsel) * 64;

  s16x8 a[4][2], b0[2][2], b1[2][2];

#define LDA(slot)                                                      \
  do {                                                                 \
    _Pragma("unroll") for (int mf = 0; mf < 4; mf++) {                 \
      a[mf][0] = *(const s16x8*)&sA[slot][arow[mf] + sw0];             \
      a[mf][1] = *(const s16x8*)&sA[slot][arow[mf] + sw1];             \
    }                                                                  \
  } while (0)
#define LDB(dst, slot)                                                 \
  do {                                                                 \
    _Pragma("unroll") for (int nf = 0; nf < 2; nf++) {                 \
      dst[nf][0] = *(const s16x8*)&sB[slot][brow[nf] + sw0];           \
      dst[nf][1] = *(const s16x8*)&sB[slot][brow[nf] + sw1];           \
    }                                                                  \
  } while (0)
#define MFMAQ(MG, NG, BB)                                              \
  do {                                                                 \
    __builtin_amdgcn_s_setprio(1);                                     \
    _Pragma("unroll") for (int mf = 0; mf < 4; mf++)                   \
    _Pragma("unroll") for (int nf = 0; nf < 2; nf++)                   \
    _Pragma("unroll") for (int ks = 0; ks < 2; ks++)                   \
      acc[MG][NG][mf][nf] = __builtin_amdgcn_mfma_f32_16x16x32_bf16(   \
          a[mf][ks], BB[nf][ks], acc[MG][NG][mf][nf], 0, 0, 0);        \
    __builtin_amdgcn_s_setprio(0);                                     \
  } while (0)

  constexpr int NS = KDIM / 64;
  // prologue: stage tile 0 in consumption-need order A0,B0,B1,A1
  STAGE_A(0, 0, 0);
  STAGE_B(0, 0, 0);
  STAGE_B(1, 1, 0);
  STAGE_A(1, 1, 0);
  WAITV(4);   // A0,B0 landed (B1,A1 may fly; needed later)
  SBAR();

#pragma unroll 2
  for (int t = 0; t < NS; ++t) {
    const int s0 = (2 * t) & 3, s1 = (2 * t + 1) & 3;
    const int sn0 = (2 * t + 2) & 3, sn1 = (2 * t + 3) & 3;
    const bool more = (t + 1 < NS);
    // ---- q0: (mg0, ng0) — reads A-half0, B-half0
    LDA(s0);
    LDB(b0, s0);
    if (more) STAGE_A(sn0, 0, t + 1);
    SBAR();
    MFMAQ(0, 0, b0);
    if (more) { WAITV(4); } else { WAITV(2); }  // ensure B1(t) landed
    SBAR();
    // ---- q1: (mg0, ng1) — reads B-half1
    LDB(b1, s1);
    if (more) STAGE_B(sn0, 0, t + 1);
    SBAR();
    MFMAQ(0, 1, b1);
    if (more) { WAITV(4); } else { WAITV(0); }  // ensure A1(t) landed
    SBAR();
    // ---- q2: (mg1, ng1) — reads A-half1
    LDA(s1);
    if (more) STAGE_B(sn1, 1, t + 1);
    SBAR();
    MFMAQ(1, 1, b1);
    SBAR();
    // ---- q3: (mg1, ng0) — pure reuse
    if (more) STAGE_A(sn1, 1, t + 1);
    SBAR();
    MFMAQ(1, 0, b0);
    if (more) { WAITV(4); }  // ensure A0(t+1),B0(t+1) landed
    SBAR();
  }
#undef LDA
#undef LDB
#undef MFMAQ
#undef STAGE_A
#undef STAGE_B

  // epilogue
  float bv[2][2];
#pragma unroll
  for (int ng = 0; ng < 2; ng++)
#pragma unroll
    for (int nf = 0; nf < 2; nf++)
      bv[ng][nf] = bias[(size_t)e * N + n0 + ng * 128 + wc * 32 + nf * 16 + rsel];
#pragma unroll
  for (int mg = 0; mg < 2; mg++) {
#pragma unroll
    for (int mf = 0; mf < 4; mf++) {
#pragma unroll
      for (int r = 0; r < 4; r++) {
        const int grow = m0 + mg * 128 + wr * 64 + mf * 16 + lhi * 4 + r;
        if (grow < mlimit) {
          if (EPI == 0) {
            ushort* hrow = Hout + (size_t)grow * N + n0;
#pragma unroll
            for (int ng = 0; ng < 2; ng++)
#pragma unroll
              for (int nf = 0; nf < 2; nf++) {
                float v = acc[mg][ng][mf][nf][r] + bv[ng][nf];
                hrow[ng * 128 + wc * 32 + nf * 16 + rsel] = f2bf(fmaxf(v, 0.0f));
              }
          } else {
            const int tok = perm[grow];
            const float sc = pmaxArr[tok];
            float* yrow = Y + (size_t)tok * N + n0;
#pragma unroll
            for (int ng = 0; ng < 2; ng++)
#pragma unroll
              for (int nf = 0; nf < 2; nf++)
                yrow[ng * 128 + wc * 32 + nf * 16 + rsel] =
                    (acc[mg][ng][mf][nf][r] + bv[ng][nf]) * sc;
          }
        }
      }
    }
  }
}

// ---------------------------------------------------------------------------
extern "C" void kernel_launch(void* const* d_in, const int* in_sizes, int n_in,
                              void* d_out, int out_size, void* d_ws, size_t ws_size,
                              hipStream_t stream) {
  const float* x  = (const float*)d_in[0];
  const float* sw = (const float*)d_in[1];
  const float* sb = (const float*)d_in[2];
  const float* w1 = (const float*)d_in[3];
  const float* b1 = (const float*)d_in[4];
  const float* w2 = (const float*)d_in[5];
  const float* b2 = (const float*)d_in[6];
  float* out = (float*)d_out;
  float* auxp = out + (size_t)NT * DOUT;

  char* wsb = (char*)d_ws;
  int*   cnt      = (int*)wsb;               // 8 ints
  float* probsum  = (float*)(wsb + 32);      // 8 floats
  int*   offsets  = (int*)(wsb + 64);        // 9 ints
  int*   routes   = (int*)(wsb + 256);
  int*   posArr   = routes + NT;
  float* pmaxArr  = (float*)(posArr + NT);
  int*   perm     = (int*)(pmaxArr + NT);
  ushort* Xg = (ushort*)(wsb + 256 + (size_t)4 * 4 * NT);           // [NT+256][DIN]
  ushort* Hg = Xg + (size_t)(NT + 256) * DIN;                       // [NT+256][DFF]
  ushort* Wt = Hg + (size_t)(NT + 256) * DFF;                       // E*DFF*DIN bf16, reused
  size_t needed = (size_t)((char*)Wt - wsb) + (size_t)NEXP * DFF * DIN * 2;
  if (ws_size < needed) return;  // insufficient scratch; fail validation visibly

  hipMemsetAsync(d_ws, 0, 64, stream);  // cnt + probsum

  router_kernel<<<NT / 64, 256, 0, stream>>>(x, sw, sb, routes, posArr, pmaxArr, cnt, probsum);
  offsets_aux_kernel<<<1, 64, 0, stream>>>(cnt, probsum, offsets, auxp);
  gather_kernel<<<NT / 4, 256, 0, stream>>>(x, routes, posArr, offsets, perm, Xg);

  // w1: [E][DIN][DFF] -> Wt [E][DFF][DIN]
  transpose_cvt_kernel<<<NEXP * (DIN / 64) * (DFF / 64), 256, 0, stream>>>(w1, Wt, DIN, DFF);
  // GEMM1: grid.y=8 covers cnt_e <= 2048 (cnt ~ 1024 +- 30, >17 sigma margin).
  moe_gemm256_kernel<DIN, 0><<<dim3(DFF / 256, 8, NEXP), 512, 0, stream>>>(
      Xg, Wt, b1, offsets, Hg, nullptr, nullptr, nullptr, DFF);

  // w2: [E][DFF][DOUT] -> Wt [E][DOUT][DFF]  (reuse Wt; stream-ordered)
  transpose_cvt_kernel<<<NEXP * (DFF / 64) * (DOUT / 64), 256, 0, stream>>>(w2, Wt, DFF, DOUT);
  moe_gemm256_kernel<DFF, 1><<<dim3(DOUT / 256, 8, NEXP), 512, 0, stream>>>(
      Hg, Wt, b2, offsets, nullptr, out, perm, pmaxArr, DOUT);
}